// Round 7
// baseline (156.661 us; speedup 1.0000x reference)
//
#include <hip/hip_runtime.h>

// MOLGCirculantLinear: 2D-tiled fused kernel with LDS staging.
// x[512][1024] f32, w[128][128][8] f32, scale[64][8] f32.
// d_out = out[512][1024] ++ phase[512][128][128][8].
//
// Block = 1024 threads (16 waves) owns an 8b x 8gy tile. x^2 and w staged in
// LDS once (64KB), then 64 (b,gy) tasks (4/wave), each: per-lane-gx circular
// conv (lane -> gx = lane, lane+64), 2KB phase store bursts, poly+scale acc,
// 6-stage butterfly reduce, 32B out write. Cuts global read traffic from
// ~268MB (R1: w re-read per wave from L2) to ~64MB.

#define NB   512
#define NGY  128
#define NGX  128
#define NK   8
#define BT   8
#define GT   8

typedef float f32x4 __attribute__((ext_vector_type(4)));

__global__ __launch_bounds__(1024, 2) void molg_tiled(
    const float* __restrict__ x,
    const float* __restrict__ w,
    const float* __restrict__ scale,
    float* __restrict__ d_out)
{
    __shared__ float lx[BT][NGX][NK];   // x^2 tile, 32KB
    __shared__ float lw[GT][NGX][NK];   // w tile,  32KB

    const int tid  = threadIdx.x;
    const int lane = tid & 63;
    const int wv   = tid >> 6;                 // 0..15
    const int bt   = blockIdx.x >> 4;          // 0..63
    const int gt   = blockIdx.x & 15;          // 0..15
    const int b0   = bt * BT;
    const int gy0  = gt * GT;

    float* out   = d_out;
    float* phase = d_out + (size_t)NB * NGY * NK;

    const float c0 = 0.02403f, c1 = -0.2699f, c2 = 1.17f,
                c3 = -2.454f,  c4 = 2.523f,  c5 = -0.08003f;

    // ---- stage: thread t loads row r=t>>7, cols c*8..c*8+7 for x^2 and w ----
    {
        const int r = tid >> 7, c = tid & 127;
        const f32x4* xs = reinterpret_cast<const f32x4*>(x + (size_t)(b0 + r) * 1024 + c * NK);
        f32x4 xa = xs[0], xb = xs[1];
        f32x4 q0 = {xa[0]*xa[0], xa[1]*xa[1], xa[2]*xa[2], xa[3]*xa[3]};
        f32x4 q1 = {xb[0]*xb[0], xb[1]*xb[1], xb[2]*xb[2], xb[3]*xb[3]};
        f32x4* ld = reinterpret_cast<f32x4*>(&lx[r][c][0]);
        ld[0] = q0; ld[1] = q1;

        const f32x4* ws = reinterpret_cast<const f32x4*>(w + ((size_t)(gy0 + r) * NGX) * NK + c * NK);
        f32x4 wa = ws[0], wb = ws[1];
        f32x4* lwp = reinterpret_cast<f32x4*>(&lw[r][c][0]);
        lwp[0] = wa; lwp[1] = wb;
    }
    __syncthreads();

    // scale[gx & 63] == scale[lane] for gx = lane and lane+64 (wave-invariant)
    const f32x4* s4 = reinterpret_cast<const f32x4*>(scale + (size_t)lane * NK);
    f32x4 sv0 = s4[0], sv1 = s4[1];
    float sv[NK] = {sv0[0], sv0[1], sv0[2], sv0[3], sv1[0], sv1[1], sv1[2], sv1[3]};

    // ---- 4 tasks per wave: task id = wv*4+tt -> (bi = id>>3, gyi = id&7) ----
#pragma unroll
    for (int tt = 0; tt < 4; ++tt) {
        const int id  = wv * 4 + tt;
        const int bi  = id >> 3;
        const int gyi = id & 7;
        const int b   = b0 + bi;
        const int gy  = gy0 + gyi;

        float* prow = phase + (((size_t)b * NGY + gy) * NGX) * NK;
        float acc[NK] = {0.f, 0.f, 0.f, 0.f, 0.f, 0.f, 0.f, 0.f};

#pragma unroll
        for (int it = 0; it < 2; ++it) {
            const int gx = lane + 64 * it;

            const f32x4* lxp = reinterpret_cast<const f32x4*>(&lx[bi][gx][0]);
            f32x4 xa = lxp[0], xb = lxp[1];
            float x2[NK] = {xa[0], xa[1], xa[2], xa[3], xb[0], xb[1], xb[2], xb[3]};

            const f32x4* lwp = reinterpret_cast<const f32x4*>(&lw[gyi][gx][0]);
            f32x4 wa = lwp[0], wb = lwp[1];
            float wf[NK] = {wa[0], wa[1], wa[2], wa[3], wb[0], wb[1], wb[2], wb[3]};

            float xr[NK];
#pragma unroll
            for (int n = 0; n < NK; ++n) {
                float s = 0.f;
#pragma unroll
                for (int m = 0; m < NK; ++m)
                    s = fmaf(wf[m], x2[(n - m) & 7], s);
                xr[n] = s;
            }

            // phase store first (let it drain under the poly/reduce)
            f32x4* pp = reinterpret_cast<f32x4*>(prow) + 2 * gx;
            f32x4 q0 = {xr[0], xr[1], xr[2], xr[3]};
            f32x4 q1 = {xr[4], xr[5], xr[6], xr[7]};
            __builtin_nontemporal_store(q0, pp);
            __builtin_nontemporal_store(q1, pp + 1);

#pragma unroll
            for (int n = 0; n < NK; ++n) {
                float v = xr[n];
                float p = fmaf(c0, v, c1);
                p = fmaf(p, v, c2);
                p = fmaf(p, v, c3);
                p = fmaf(p, v, c4);
                p = fmaf(p, v, c5);
                p = fminf(fmaxf(p, 0.f), 1.f);
                acc[n] = fmaf(p, sv[n], acc[n]);
            }
        }

        // full butterfly: all lanes end with total sums for all 8 k
#pragma unroll
        for (int off = 1; off < 64; off <<= 1)
#pragma unroll
            for (int k = 0; k < NK; ++k)
                acc[k] += __shfl_xor(acc[k], off, 64);

        if (lane < 2) {
            f32x4* o4 = reinterpret_cast<f32x4*>(out + (size_t)b * 1024 + gy * NK) + lane;
            f32x4 v;
            if (lane == 0) v = (f32x4){fmaf(2.f, acc[0], -128.f), fmaf(2.f, acc[1], -128.f),
                                       fmaf(2.f, acc[2], -128.f), fmaf(2.f, acc[3], -128.f)};
            else           v = (f32x4){fmaf(2.f, acc[4], -128.f), fmaf(2.f, acc[5], -128.f),
                                       fmaf(2.f, acc[6], -128.f), fmaf(2.f, acc[7], -128.f)};
            *o4 = v;
        }
    }
}

extern "C" void kernel_launch(void* const* d_in, const int* in_sizes, int n_in,
                              void* d_out, int out_size, void* d_ws, size_t ws_size,
                              hipStream_t stream) {
    const float* x     = (const float*)d_in[0];
    const float* w     = (const float*)d_in[1];
    const float* scale = (const float*)d_in[2];
    float* out = (float*)d_out;

    dim3 grid(1024);     // 64 b-tiles x 16 gy-tiles
    dim3 block(1024);    // 16 waves; 64KB LDS -> 2 blocks/CU
    hipLaunchKernelGGL(molg_tiled, grid, block, 0, stream, x, w, scale, out);
}

// Round 8
// 56.460 us; speedup vs baseline: 2.7747x; 2.7747x over previous
//
#include <hip/hip_runtime.h>

// MOLGCirculantLinear: software-pipelined fused kernel.
// x[512][1024] f32, w[128][128][8] f32, scale[64][8] f32.
// d_out = out[512][1024] ++ phase[512][128][128][8].
//
// One wave per (b, 4 consecutive gy). Lane i owns (gxs = i>>1, kq = i&1);
// 4 its of 32 gx each cover gx 0..127. x^2 pre-rotated by 4*kq once per wave
// (register-resident, reused across 4 gy). w for gy j+1 prefetched during
// gy j's conv/store/poly. Phase stores: one f32x4 per lane per it -> each
// instruction writes a dense, line-aligned 1KB burst (plain stores, L2 merge).
// Reduces (5-stage parity butterfly x4 gy) deferred to wave tail.

#define NB   512
#define NGY  128
#define NGX  128
#define NK   8

typedef float f32x4 __attribute__((ext_vector_type(4)));

__global__ __launch_bounds__(256, 2) void molg_pipe(
    const float* __restrict__ x,
    const float* __restrict__ w,
    const float* __restrict__ scale,
    float* __restrict__ d_out)
{
    const int lane = threadIdx.x & 63;
    const int wv   = threadIdx.x >> 6;        // 0..3
    const int b    = blockIdx.x >> 3;         // 512 b
    const int gy0  = (blockIdx.x & 7) * 16 + wv * 4;

    const int gxs = lane >> 1;                // 0..31
    const int kq  = lane & 1;                 // k-half

    float* out   = d_out;
    float* phase = d_out + (size_t)NB * NGY * NK;

    const float c0 = 0.02403f, c1 = -0.2699f, c2 = 1.17f,
                c3 = -2.454f,  c4 = 2.523f,  c5 = -0.08003f;

    // ---- per-wave preload: x^2 rotated by 4*kq, for 4 gx positions ----
    float y[4][NK];
#pragma unroll
    for (int it = 0; it < 4; ++it) {
        const int gx = 32 * it + gxs;
        const f32x4* xp = reinterpret_cast<const f32x4*>(x + (size_t)b * 1024 + gx * NK);
        f32x4 a = xp[0], c = xp[1];
        float t[NK] = {a[0]*a[0], a[1]*a[1], a[2]*a[2], a[3]*a[3],
                       c[0]*c[0], c[1]*c[1], c[2]*c[2], c[3]*c[3]};
#pragma unroll
        for (int q = 0; q < NK; ++q)
            y[it][q] = kq ? t[(q + 4) & 7] : t[q];
    }

    // scale: gx&63 = gxs (it even) or gxs+32 (it odd)
    const f32x4 sve = *reinterpret_cast<const f32x4*>(scale + (size_t)gxs * NK + 4 * kq);
    const f32x4 svo = *reinterpret_cast<const f32x4*>(scale + (size_t)(gxs + 32) * NK + 4 * kq);

    // ---- prefetch w for gy0 ----
    f32x4 wbuf[2][4][2];
#pragma unroll
    for (int it = 0; it < 4; ++it) {
        const f32x4* wp = reinterpret_cast<const f32x4*>(
            w + ((size_t)gy0 * NGX + 32 * it + gxs) * NK);
        wbuf[0][it][0] = wp[0];
        wbuf[0][it][1] = wp[1];
    }

    float acc[4][4];
#pragma unroll
    for (int j = 0; j < 4; ++j)
#pragma unroll
        for (int q = 0; q < 4; ++q) acc[j][q] = 0.f;

    // ---- pipelined gy loop ----
#pragma unroll
    for (int j = 0; j < 4; ++j) {
        const int gy = gy0 + j;

        if (j < 3) {   // prefetch next gy's w while this gy computes/stores
#pragma unroll
            for (int it = 0; it < 4; ++it) {
                const f32x4* wp = reinterpret_cast<const f32x4*>(
                    w + ((size_t)(gy + 1) * NGX + 32 * it + gxs) * NK);
                wbuf[(j + 1) & 1][it][0] = wp[0];
                wbuf[(j + 1) & 1][it][1] = wp[1];
            }
        }

        f32x4* prow4 = reinterpret_cast<f32x4*>(
            phase + (((size_t)b * NGY + gy) * NGX) * NK);

#pragma unroll
        for (int it = 0; it < 4; ++it) {
            f32x4 wa = wbuf[j & 1][it][0], wb = wbuf[j & 1][it][1];
            float wf[NK] = {wa[0], wa[1], wa[2], wa[3], wb[0], wb[1], wb[2], wb[3]};

            float xr[4];
#pragma unroll
            for (int n = 0; n < 4; ++n) {
                float s = 0.f;
#pragma unroll
                for (int m = 0; m < NK; ++m)
                    s = fmaf(wf[m], y[it][(n - m) & 7], s);
                xr[n] = s;
            }

            // dense 1KB line-aligned burst: lane i -> byte 16*i
            f32x4 q = {xr[0], xr[1], xr[2], xr[3]};
            prow4[64 * it + lane] = q;

            const f32x4 sv = (it & 1) ? svo : sve;
#pragma unroll
            for (int n = 0; n < 4; ++n) {
                float v = xr[n];
                float p = fmaf(c0, v, c1);
                p = fmaf(p, v, c2);
                p = fmaf(p, v, c3);
                p = fmaf(p, v, c4);
                p = fmaf(p, v, c5);
                p = fminf(fmaxf(p, 0.f), 1.f);
                acc[j][n] = fmaf(p, sv[n], acc[j][n]);
            }
        }
    }

    // ---- tail: 4 parity-preserving butterflies + out stores ----
#pragma unroll
    for (int j = 0; j < 4; ++j) {
#pragma unroll
        for (int off = 2; off < 64; off <<= 1)
#pragma unroll
            for (int n = 0; n < 4; ++n)
                acc[j][n] += __shfl_xor(acc[j][n], off, 64);

        if (lane < 2) {   // lane0: k0..3, lane1: k4..7
            f32x4 v = {fmaf(2.f, acc[j][0], -128.f), fmaf(2.f, acc[j][1], -128.f),
                       fmaf(2.f, acc[j][2], -128.f), fmaf(2.f, acc[j][3], -128.f)};
            *(reinterpret_cast<f32x4*>(out + (size_t)b * 1024 + (gy0 + j) * NK) + lane) = v;
        }
    }
}

extern "C" void kernel_launch(void* const* d_in, const int* in_sizes, int n_in,
                              void* d_out, int out_size, void* d_ws, size_t ws_size,
                              hipStream_t stream) {
    const float* x     = (const float*)d_in[0];
    const float* w     = (const float*)d_in[1];
    const float* scale = (const float*)d_in[2];
    float* out = (float*)d_out;

    dim3 grid(4096);    // 512 b x 8 gy-groups; one wave per (b, 4 gy)
    dim3 block(256);
    hipLaunchKernelGGL(molg_pipe, grid, block, 0, stream, x, w, scale, out);
}

// Round 9
// 55.877 us; speedup vs baseline: 2.8037x; 1.0104x over previous
//
#include <hip/hip_runtime.h>

// MOLGCirculantLinear: software-pipelined fused kernel (R7 structure).
// R8 change: phase stores are nontemporal — each store instruction covers a
// full aligned 1KB burst (lane i -> byte 16*i), so nt streams exact bytes
// past L2 without the half-line merge problem R6's nt stores had.
//
// One wave per (b, 4 consecutive gy). Lane i owns (gxs = i>>1, kq = i&1);
// x^2 pre-rotated by 4*kq once per wave; w for gy j+1 prefetched during gy j;
// reduces deferred to wave tail.

#define NB   512
#define NGY  128
#define NGX  128
#define NK   8

typedef float f32x4 __attribute__((ext_vector_type(4)));

__global__ __launch_bounds__(256, 2) void molg_pipe(
    const float* __restrict__ x,
    const float* __restrict__ w,
    const float* __restrict__ scale,
    float* __restrict__ d_out)
{
    const int lane = threadIdx.x & 63;
    const int wv   = threadIdx.x >> 6;        // 0..3
    const int b    = blockIdx.x >> 3;         // 512 b
    const int gy0  = (blockIdx.x & 7) * 16 + wv * 4;

    const int gxs = lane >> 1;                // 0..31
    const int kq  = lane & 1;                 // k-half

    float* out   = d_out;
    float* phase = d_out + (size_t)NB * NGY * NK;

    const float c0 = 0.02403f, c1 = -0.2699f, c2 = 1.17f,
                c3 = -2.454f,  c4 = 2.523f,  c5 = -0.08003f;

    // ---- per-wave preload: x^2 rotated by 4*kq, for 4 gx positions ----
    float y[4][NK];
#pragma unroll
    for (int it = 0; it < 4; ++it) {
        const int gx = 32 * it + gxs;
        const f32x4* xp = reinterpret_cast<const f32x4*>(x + (size_t)b * 1024 + gx * NK);
        f32x4 a = xp[0], c = xp[1];
        float t[NK] = {a[0]*a[0], a[1]*a[1], a[2]*a[2], a[3]*a[3],
                       c[0]*c[0], c[1]*c[1], c[2]*c[2], c[3]*c[3]};
#pragma unroll
        for (int q = 0; q < NK; ++q)
            y[it][q] = kq ? t[(q + 4) & 7] : t[q];
    }

    // scale: gx&63 = gxs (it even) or gxs+32 (it odd)
    const f32x4 sve = *reinterpret_cast<const f32x4*>(scale + (size_t)gxs * NK + 4 * kq);
    const f32x4 svo = *reinterpret_cast<const f32x4*>(scale + (size_t)(gxs + 32) * NK + 4 * kq);

    // ---- prefetch w for gy0 ----
    f32x4 wbuf[2][4][2];
#pragma unroll
    for (int it = 0; it < 4; ++it) {
        const f32x4* wp = reinterpret_cast<const f32x4*>(
            w + ((size_t)gy0 * NGX + 32 * it + gxs) * NK);
        wbuf[0][it][0] = wp[0];
        wbuf[0][it][1] = wp[1];
    }

    float acc[4][4];
#pragma unroll
    for (int j = 0; j < 4; ++j)
#pragma unroll
        for (int q = 0; q < 4; ++q) acc[j][q] = 0.f;

    // ---- pipelined gy loop ----
#pragma unroll
    for (int j = 0; j < 4; ++j) {
        const int gy = gy0 + j;

        if (j < 3) {   // prefetch next gy's w while this gy computes/stores
#pragma unroll
            for (int it = 0; it < 4; ++it) {
                const f32x4* wp = reinterpret_cast<const f32x4*>(
                    w + ((size_t)(gy + 1) * NGX + 32 * it + gxs) * NK);
                wbuf[(j + 1) & 1][it][0] = wp[0];
                wbuf[(j + 1) & 1][it][1] = wp[1];
            }
        }

        f32x4* prow4 = reinterpret_cast<f32x4*>(
            phase + (((size_t)b * NGY + gy) * NGX) * NK);

#pragma unroll
        for (int it = 0; it < 4; ++it) {
            f32x4 wa = wbuf[j & 1][it][0], wb = wbuf[j & 1][it][1];
            float wf[NK] = {wa[0], wa[1], wa[2], wa[3], wb[0], wb[1], wb[2], wb[3]};

            float xr[4];
#pragma unroll
            for (int n = 0; n < 4; ++n) {
                float s = 0.f;
#pragma unroll
                for (int m = 0; m < NK; ++m)
                    s = fmaf(wf[m], y[it][(n - m) & 7], s);
                xr[n] = s;
            }

            // dense 1KB line-aligned burst: lane i -> byte 16*i (nontemporal)
            f32x4 q = {xr[0], xr[1], xr[2], xr[3]};
            __builtin_nontemporal_store(q, prow4 + 64 * it + lane);

            const f32x4 sv = (it & 1) ? svo : sve;
#pragma unroll
            for (int n = 0; n < 4; ++n) {
                float v = xr[n];
                float p = fmaf(c0, v, c1);
                p = fmaf(p, v, c2);
                p = fmaf(p, v, c3);
                p = fmaf(p, v, c4);
                p = fmaf(p, v, c5);
                p = fminf(fmaxf(p, 0.f), 1.f);
                acc[j][n] = fmaf(p, sv[n], acc[j][n]);
            }
        }
    }

    // ---- tail: 4 parity-preserving butterflies + out stores ----
#pragma unroll
    for (int j = 0; j < 4; ++j) {
#pragma unroll
        for (int off = 2; off < 64; off <<= 1)
#pragma unroll
            for (int n = 0; n < 4; ++n)
                acc[j][n] += __shfl_xor(acc[j][n], off, 64);

        if (lane < 2) {   // lane0: k0..3, lane1: k4..7
            f32x4 v = {fmaf(2.f, acc[j][0], -128.f), fmaf(2.f, acc[j][1], -128.f),
                       fmaf(2.f, acc[j][2], -128.f), fmaf(2.f, acc[j][3], -128.f)};
            *(reinterpret_cast<f32x4*>(out + (size_t)b * 1024 + (gy0 + j) * NK) + lane) = v;
        }
    }
}

extern "C" void kernel_launch(void* const* d_in, const int* in_sizes, int n_in,
                              void* d_out, int out_size, void* d_ws, size_t ws_size,
                              hipStream_t stream) {
    const float* x     = (const float*)d_in[0];
    const float* w     = (const float*)d_in[1];
    const float* scale = (const float*)d_in[2];
    float* out = (float*)d_out;

    dim3 grid(4096);    // 512 b x 8 gy-groups; one wave per (b, 4 gy)
    dim3 block(256);
    hipLaunchKernelGGL(molg_pipe, grid, block, 0, stream, x, w, scale, out);
}